// Round 10
// baseline (427.196 us; speedup 1.0000x reference)
//
#include <hip/hip_runtime.h>
#include <math.h>

#define NPTS 262144
#define TM   64      // points per block
#define NTHR 256     // 4 waves
#define AS   264     // act row stride (bf16 elems): 528B = 33*16B rows -> 2-way LDS aliasing (free)
#define PS   72      // pbuf row stride: 144B = 9*16B

#define WS_SHORTS 593920   // prepacked weight image (bf16 elems)

typedef short  short8  __attribute__((ext_vector_type(8)));
typedef float  floatx4 __attribute__((ext_vector_type(4)));

__device__ __forceinline__ unsigned short f2b(float f) {  // RNE
  union { float f; unsigned int i; } v; v.f = f;
  return (unsigned short)((v.i + 0x7fffu + ((v.i >> 16) & 1u)) >> 16);
}
__device__ __forceinline__ float b2f(unsigned short u) {
  union { unsigned int i; float f; } v; v.i = ((unsigned int)u) << 16; return v.f;
}

// ---------------- weight prepack (identical image since R5) ----------------
// u = nf*512 + lane*8 + j  ->  W[n = nf*16 + (lane&15)][k = c*32 + (lane>>4)*8 + j]
struct PrepArgs {
  const float* src[10];
  unsigned short* ws;
  long long dst[10];
  int steps[10];
  int ksrc[10];
  int mode[10];   // 0: direct, 1: zero-pad >=ksrc, 2: L5 remap [base(256)|p(63)|pad]
  int nf16[10];
};

__global__ __launch_bounds__(256) void prep_weights(PrepArgs P) {
  int jl = blockIdx.x, c = blockIdx.y;
  if (c >= P.steps[jl]) return;
  const int NF = P.nf16[jl], tot = NF * 512;
  const float* src = P.src[jl];
  const int Ks = P.ksrc[jl], mode = P.mode[jl];
  unsigned short* dst = P.ws + P.dst[jl] + (long long)c * tot;
  for (int u = threadIdx.x; u < tot; u += 256) {
    int j = u & 7, lane = (u >> 3) & 63, nf = u >> 9;
    int n  = nf * 16 + (lane & 15);
    int kp = c * 32 + ((lane >> 4) << 3) + j;
    int sc;
    if (mode == 0)      sc = kp;
    else if (mode == 1) sc = (kp < Ks) ? kp : -1;
    else                sc = (kp < 256) ? kp + 63 : (kp < Ks ? kp - 256 : -1);
    dst[u] = (sc >= 0) ? f2b(src[(long long)n * Ks + sc]) : (unsigned short)0;
  }
}

struct NerfArgs {
  const float* pts;
  const float* dirs;
  const unsigned short* ws;
  const float* bias[10];   // bb0..bb7, brm, br0
  const float* Wsig;
  const float* bsig;
  const float* Wr1;
  const float* br1;
  float* out;
};

// One layer: relu(act[64 x K] @ W^T + bias) -> act (in-place safe).
// TRANSPOSE TRICK: D^T = (W-tile) x (act-tile); each lane gets 4 contiguous
// channels for point col=lane&15 -> 8B ds_write_b64 epilogue.
// W-frags stream from global (L2-hot prepacked image) with a TWO-deep
// rotating prefetch: R9's 1-deep gave a load->use gap of ~1 K-step (~120 cyc)
// vs ~200-225 cyc L2 latency -> per-step vmcnt stall. 2-deep makes the gap
// ~2 steps (~250 cyc) > latency. acc is initialized with the BIAS (bv regs
// die after init -> no K-loop pressure; epilogue drops 4 v_add per frag).
// act-frags from PADDED LDS: every ds address = loop-invariant base +
// compile-time immediate (R8's runtime swizzle math cost 42% VALUBusy).
// REGISTER BUDGET (gfx950 unified VGPR/AGPR): 64 AGPR acc + 48 wreg + ~35
// misc ~= 147 < 170 cap at min-waves 3. min-waves 4 (128 cap) spills 1.3GB
// (R6); runtime layer params spill ~250MB (R7). If FETCH_SIZE jumps >>10MB,
// the prefetch depth spilled: revert to 2-buffer.
template<int NFTOT, int NFW, int STEPS, int STEPS0, int LD0, int LD1>
__device__ __forceinline__ void gemm_g(
    const unsigned short* wimg,
    const short* seg0, const short* seg1,
    const float* bias, short* dst, int tid)
{
  const int lane = tid & 63, wave = tid >> 6;
  const int prow = lane & 15;
  const int r4   = (lane >> 4) * 4;
  const int koff = (lane >> 4) * 8;

  // acc = bias (broadcast across points); bv dead after this block
  floatx4 acc[4][NFW];
  {
    float4 bv[NFW];
#pragma unroll
    for (int i = 0; i < NFW; ++i)
      bv[i] = *(const float4*)(bias + (wave * NFW + i) * 16 + r4);
#pragma unroll
    for (int mf = 0; mf < 4; ++mf)
#pragma unroll
      for (int i = 0; i < NFW; ++i) {
        acc[mf][i][0] = bv[i].x; acc[mf][i][1] = bv[i].y;
        acc[mf][i][2] = bv[i].z; acc[mf][i][3] = bv[i].w;
      }
  }

  const unsigned short* wl = wimg + (size_t)(wave * NFW) * 512 + (size_t)lane * 8;
  const short* b0 = seg0 + (size_t)prow * LD0 + koff;   // loop-invariant bases
  const short* b1 = seg1 + (size_t)prow * LD1 + koff;

  // 2-deep rotating weight prefetch; all indices compile-time under unroll
  short8 wreg[3][NFW];
#pragma unroll
  for (int i = 0; i < NFW; ++i) wreg[0][i] = *(const short8*)(wl + i * 512);
  if (STEPS > 1) {
#pragma unroll
    for (int i = 0; i < NFW; ++i)
      wreg[1][i] = *(const short8*)(wl + (size_t)(NFTOT * 512) + i * 512);
  }

#pragma unroll
  for (int s = 0; s < STEPS; ++s) {
    if (s + 2 < STEPS) {
      const unsigned short* wn = wl + (size_t)(s + 2) * (NFTOT * 512);
#pragma unroll
      for (int i = 0; i < NFW; ++i)
        wreg[(s + 2) % 3][i] = *(const short8*)(wn + i * 512);
    }
    short8 b[4];
#pragma unroll
    for (int mf = 0; mf < 4; ++mf) {
      // act[point = mf*16+prow][kl+koff .. +7]; offset is a compile-time imm
      if (s < STEPS0) b[mf] = *(const short8*)(b0 + mf * 16 * LD0 + s * 32);
      else            b[mf] = *(const short8*)(b1 + mf * 16 * LD1 + (s - STEPS0) * 32);
    }
#pragma unroll
    for (int mf = 0; mf < 4; ++mf)
#pragma unroll
      for (int i = 0; i < NFW; ++i)
        acc[mf][i] = __builtin_amdgcn_mfma_f32_16x16x32_bf16(wreg[s % 3][i], b[mf], acc[mf][i], 0, 0, 0);
  }
  __syncthreads();   // all waves' K-loop reads complete before in-place writes
  // D^T C/D layout: channel n = (wave*NFW+i)*16 + r4 + r, point = mf*16 + prow
  short* dstb = dst + (size_t)prow * AS + wave * NFW * 16 + r4;  // loop-invariant base
#pragma unroll
  for (int i = 0; i < NFW; ++i) {
#pragma unroll
    for (int mf = 0; mf < 4; ++mf) {
      float v0 = fmaxf(acc[mf][i][0], 0.f);
      float v1 = fmaxf(acc[mf][i][1], 0.f);
      float v2 = fmaxf(acc[mf][i][2], 0.f);
      float v3 = fmaxf(acc[mf][i][3], 0.f);
      int2 pk;
      pk.x = (int)((unsigned int)f2b(v0) | ((unsigned int)f2b(v1) << 16));
      pk.y = (int)((unsigned int)f2b(v2) | ((unsigned int)f2b(v3) << 16));
      *(int2*)(dstb + mf * 16 * AS + i * 16) = pk;   // compile-time imm offset
    }
  }
  __syncthreads();
}

__global__ __launch_bounds__(NTHR, 3)   // 3 blocks/CU: see register-budget note
void nerf_fused(NerfArgs A) {
  __shared__ alignas(16) short act[TM * AS];   // 33792 B
  __shared__ alignas(16) short pbuf[TM * PS];  //  9216 B  -> 43008 B total
  const int tid = threadIdx.x;
  const int lane = tid & 63, wave = tid >> 6;
  const size_t gbase = (size_t)blockIdx.x * TM;

  // pts embed, parallel over (row, dim): 192 threads; col 63 zero by the rest
  if (tid < 192) {
    int row = tid & 63, dim = tid >> 6;
    float x = A.pts[(gbase + row) * 3 + dim];
    short* pr = pbuf + row * PS;
    pr[dim] = (short)f2b(x);
    float fr = 1.f;
    for (int q = 0; q < 10; ++q) {
      pr[3 + q * 6 + dim]     = (short)f2b(sinf(x * fr));
      pr[3 + q * 6 + 3 + dim] = (short)f2b(cosf(x * fr));
      fr *= 2.f;
    }
  } else {
    pbuf[(tid - 192) * PS + 63] = 0;
  }
  __syncthreads();

  const short* actp = act;
  short*       actw = act;
  const short* pbp  = pbuf;
  const unsigned short* ws = A.ws;

  gemm_g<16, 4,  2, 2, PS, AS>(ws + 0,      pbp,  actp, A.bias[0], actw, tid);
  gemm_g<16, 4,  8, 8, AS, AS>(ws + 16384,  actp, actp, A.bias[1], actw, tid);
  gemm_g<16, 4,  8, 8, AS, AS>(ws + 81920,  actp, actp, A.bias[2], actw, tid);
  gemm_g<16, 4,  8, 8, AS, AS>(ws + 147456, actp, actp, A.bias[3], actw, tid);
  gemm_g<16, 4,  8, 8, AS, AS>(ws + 212992, actp, actp, A.bias[4], actw, tid);
  gemm_g<16, 4, 10, 8, AS, PS>(ws + 278528, actp, pbp,  A.bias[5], actw, tid);

  // p dead: dirs embed into pbuf (cols 0..26; 27..31 zero) + d output.
  // d written as 27 CONTIGUOUS f32 per thread (R5 pattern, measured clean
  // WRITE=31MB). Scattered per-dim stores (R6-R8) caused partial-line RMW
  // thrash under L2 pressure: WRITE 269MB / FETCH +100MB. Keep contiguous.
  if (tid >= 64 && tid < 128) {
    int row = tid - 64;
    size_t g = gbase + row;
    float x0 = A.dirs[g * 3 + 0];
    float x1 = A.dirs[g * 3 + 1];
    float x2 = A.dirs[g * 3 + 2];
    float vals[27];
    vals[0] = x0; vals[1] = x1; vals[2] = x2;
    float fr = 1.f;
    for (int q = 0; q < 4; ++q) {
      vals[3 + q * 6 + 0] = sinf(x0 * fr);
      vals[3 + q * 6 + 1] = sinf(x1 * fr);
      vals[3 + q * 6 + 2] = sinf(x2 * fr);
      vals[3 + q * 6 + 3] = cosf(x0 * fr);
      vals[3 + q * 6 + 4] = cosf(x1 * fr);
      vals[3 + q * 6 + 5] = cosf(x2 * fr);
      fr *= 2.f;
    }
    short* dr = pbuf + row * PS;
    float* og = A.out + (size_t)4 * NPTS + g * 27;
    for (int j = 0; j < 27; ++j) {
      dr[j] = (short)f2b(vals[j]);
      og[j] = vals[j];
    }
    for (int j = 27; j < 32; ++j) dr[j] = 0;
  }
  // no barrier needed: L6's epilogue barriers order these writes before r0's reads

  gemm_g<16, 4,  8, 8, AS, AS>(ws + 360448, actp, actp, A.bias[6], actw, tid);
  gemm_g<16, 4,  8, 8, AS, AS>(ws + 425984, actp, actp, A.bias[7], actw, tid);

  // sigma head (SIGMA_MUL=0 -> passthrough): point = wave*16+(lane&15), k-quarter = lane>>4
  {
    int p = wave * 16 + (lane & 15);
    int q = lane >> 4;
    float s = 0.f;
    for (int c8 = 0; c8 < 8; ++c8) {
      int k0 = q * 64 + c8 * 8;
      short8 v = *(const short8*)(act + p * AS + k0);
      const float4 w0 = *(const float4*)(A.Wsig + k0);
      const float4 w1 = *(const float4*)(A.Wsig + k0 + 4);
      s += b2f((unsigned short)v[0]) * w0.x + b2f((unsigned short)v[1]) * w0.y
         + b2f((unsigned short)v[2]) * w0.z + b2f((unsigned short)v[3]) * w0.w
         + b2f((unsigned short)v[4]) * w1.x + b2f((unsigned short)v[5]) * w1.y
         + b2f((unsigned short)v[6]) * w1.z + b2f((unsigned short)v[7]) * w1.w;
    }
    s += __shfl_xor(s, 16);
    s += __shfl_xor(s, 32);
    if (q == 0) A.out[(size_t)3 * NPTS + gbase + p] = s + A.bsig[0];
  }
  // sigma reads of act are ordered before rm's in-place writes by rm's pre-epilogue barrier

  gemm_g<16, 4,  8, 8, AS, AS>(ws + 491520, actp, actp, A.bias[8], actw, tid);
  gemm_g< 8, 2,  9, 8, AS, PS>(ws + 557056, actp, pbp,  A.bias[9], actw, tid);

  // rgb head: sigmoid(fea[128] @ Wr1^T + br1): point = wave*16+(lane&15), k-quarter = lane>>4
  {
    int p = wave * 16 + (lane & 15);
    int q = lane >> 4;
    float s0 = 0.f, s1 = 0.f, s2 = 0.f;
    for (int c8 = 0; c8 < 4; ++c8) {
      int k0 = q * 32 + c8 * 8;
      short8 v = *(const short8*)(act + p * AS + k0);
#pragma unroll
      for (int j = 0; j < 8; ++j) {
        float fv = b2f((unsigned short)v[j]);
        s0 += fv * A.Wr1[k0 + j];
        s1 += fv * A.Wr1[128 + k0 + j];
        s2 += fv * A.Wr1[256 + k0 + j];
      }
    }
    s0 += __shfl_xor(s0, 16); s0 += __shfl_xor(s0, 32);
    s1 += __shfl_xor(s1, 16); s1 += __shfl_xor(s1, 32);
    s2 += __shfl_xor(s2, 16); s2 += __shfl_xor(s2, 32);
    if (q == 0) {
      size_t g = gbase + p;
      A.out[g * 3 + 0] = 1.f / (1.f + expf(-(s0 + A.br1[0])));
      A.out[g * 3 + 1] = 1.f / (1.f + expf(-(s1 + A.br1[1])));
      A.out[g * 3 + 2] = 1.f / (1.f + expf(-(s2 + A.br1[2])));
    }
  }
}

extern "C" void kernel_launch(void* const* d_in, const int* in_sizes, int n_in,
                              void* d_out, int out_size, void* d_ws, size_t ws_size,
                              hipStream_t stream) {
  // input order: pts, dirs, (Wb_i, bb_i)*8, Wsig, bsig, Wrm, brm, Wr0, br0, Wr1, br1
  PrepArgs pp;
  const int       widx[10]  = {2, 4, 6, 8, 10, 12, 14, 16, 20, 22};
  const long long doffs[10] = {0, 16384, 81920, 147456, 212992, 278528,
                               360448, 425984, 491520, 557056};
  const int stv[10] = {2, 8, 8, 8, 8, 10, 8, 8, 8, 9};
  const int ksv[10] = {63, 256, 256, 256, 256, 319, 256, 256, 256, 283};
  const int mdv[10] = {1, 0, 0, 0, 0, 2, 0, 0, 0, 1};
  const int nfv[10] = {16, 16, 16, 16, 16, 16, 16, 16, 16, 8};
  pp.ws = (unsigned short*)d_ws;   // needs WS_SHORTS*2 = 1.19 MB (verified fits)
  for (int j = 0; j < 10; ++j) {
    pp.src[j] = (const float*)d_in[widx[j]];
    pp.dst[j] = doffs[j]; pp.steps[j] = stv[j]; pp.ksrc[j] = ksv[j];
    pp.mode[j] = mdv[j]; pp.nf16[j] = nfv[j];
  }
  prep_weights<<<dim3(10, 10), dim3(256), 0, stream>>>(pp);

  NerfArgs na;
  na.pts  = (const float*)d_in[0];
  na.dirs = (const float*)d_in[1];
  na.ws   = (const unsigned short*)d_ws;
  for (int i = 0; i < 8; ++i) na.bias[i] = (const float*)d_in[3 + 2 * i];
  na.bias[8] = (const float*)d_in[21];  // brm
  na.bias[9] = (const float*)d_in[23];  // br0
  na.Wsig = (const float*)d_in[18];
  na.bsig = (const float*)d_in[19];
  na.Wr1  = (const float*)d_in[24];
  na.br1  = (const float*)d_in[25];
  na.out  = (float*)d_out;
  nerf_fused<<<dim3(NPTS / TM), dim3(NTHR), 0, stream>>>(na);
}

// Round 11
// 409.305 us; speedup vs baseline: 1.0437x; 1.0437x over previous
//
#include <hip/hip_runtime.h>
#include <hip/hip_bf16.h>
#include <math.h>

#define NPTS 262144
#define TM   64      // points per block
#define NTHR 256     // 4 waves
// LDS strides chosen for the TRANSPOSED frag access (lane = g*16+p reads
// row p at k-offset g*8): bank-quad = p*(AS/8) + g (mod 32). AS/8 must be
// ===2 (mod 32) so 2p+g covers each bank exactly twice (2-way = free, m136).
// R9/R10's AS=264 (33 units === 1) gave p+g -> 4-way conflicts = 3.25e7
// counter = ~16% of cycles.
#define AS   272     // 34*16B rows (34 === 2 mod 32)
#define PS   80      // 10*16B rows (10 === 2 mod 32)

#define WS_SHORTS 593920   // prepacked weight image (bf16 elems)

typedef short  short8  __attribute__((ext_vector_type(8)));
typedef float  floatx4 __attribute__((ext_vector_type(4)));

__device__ __forceinline__ unsigned short f2b(float f) {  // RNE
  union { float f; unsigned int i; } v; v.f = f;
  return (unsigned short)((v.i + 0x7fffu + ((v.i >> 16) & 1u)) >> 16);
}
__device__ __forceinline__ float b2f(unsigned short u) {
  union { unsigned int i; float f; } v; v.i = ((unsigned int)u) << 16; return v.f;
}

// ---------------- weight prepack (identical image since R5) ----------------
// u = nf*512 + lane*8 + j  ->  W[n = nf*16 + (lane&15)][k = c*32 + (lane>>4)*8 + j]
struct PrepArgs {
  const float* src[10];
  unsigned short* ws;
  long long dst[10];
  int steps[10];
  int ksrc[10];
  int mode[10];   // 0: direct, 1: zero-pad >=ksrc, 2: L5 remap [base(256)|p(63)|pad]
  int nf16[10];
};

__global__ __launch_bounds__(256) void prep_weights(PrepArgs P) {
  int jl = blockIdx.x, c = blockIdx.y;
  if (c >= P.steps[jl]) return;
  const int NF = P.nf16[jl], tot = NF * 512;
  const float* src = P.src[jl];
  const int Ks = P.ksrc[jl], mode = P.mode[jl];
  unsigned short* dst = P.ws + P.dst[jl] + (long long)c * tot;
  for (int u = threadIdx.x; u < tot; u += 256) {
    int j = u & 7, lane = (u >> 3) & 63, nf = u >> 9;
    int n  = nf * 16 + (lane & 15);
    int kp = c * 32 + ((lane >> 4) << 3) + j;
    int sc;
    if (mode == 0)      sc = kp;
    else if (mode == 1) sc = (kp < Ks) ? kp : -1;
    else                sc = (kp < 256) ? kp + 63 : (kp < Ks ? kp - 256 : -1);
    dst[u] = (sc >= 0) ? f2b(src[(long long)n * Ks + sc]) : (unsigned short)0;
  }
}

struct NerfArgs {
  const float* pts;
  const float* dirs;
  const unsigned short* ws;
  const float* bias[10];   // bb0..bb7, brm, br0
  const float* Wsig;
  const float* bsig;
  const float* Wr1;
  const float* br1;
  float* out;
};

// One layer: relu(act[64 x K] @ W^T + bias) -> act (in-place safe).
// TRANSPOSE TRICK: D^T = (W-tile) x (act-tile); each lane gets 4 contiguous
// channels for point col=lane&15 -> 8B ds_write_b64 epilogue (packed
// v_cvt_pk_bf16_f32 via __float22bfloat162_rn, RNE = bit-identical to f2b).
// W-frags stream from global (L2-hot prepacked image), 2-deep rotating
// register prefetch (R10: neutral vs 1-deep, kept). acc starts at BIAS.
// act-frags from PADDED LDS: every ds address = loop-invariant base +
// compile-time immediate (runtime swizzle math cost 42% VALUBusy in R8).
// REGISTER BUDGET (gfx950 unified VGPR/AGPR): 64 AGPR acc + 48 wreg + ~35
// misc ~= 147 < 170 cap at min-waves 3. min-waves 4 (128 cap) spills 1.3GB
// (R6); runtime layer params spill ~250MB (R7). FETCH_SIZE >> 10MB = spill.
template<int NFTOT, int NFW, int STEPS, int STEPS0, int LD0, int LD1>
__device__ __forceinline__ void gemm_g(
    const unsigned short* wimg,
    const short* seg0, const short* seg1,
    const float* bias, short* dst, int tid)
{
  const int lane = tid & 63, wave = tid >> 6;
  const int prow = lane & 15;
  const int r4   = (lane >> 4) * 4;
  const int koff = (lane >> 4) * 8;

  // acc = bias (broadcast across points); bv dead after this block
  floatx4 acc[4][NFW];
  {
    float4 bv[NFW];
#pragma unroll
    for (int i = 0; i < NFW; ++i)
      bv[i] = *(const float4*)(bias + (wave * NFW + i) * 16 + r4);
#pragma unroll
    for (int mf = 0; mf < 4; ++mf)
#pragma unroll
      for (int i = 0; i < NFW; ++i) {
        acc[mf][i][0] = bv[i].x; acc[mf][i][1] = bv[i].y;
        acc[mf][i][2] = bv[i].z; acc[mf][i][3] = bv[i].w;
      }
  }

  const unsigned short* wl = wimg + (size_t)(wave * NFW) * 512 + (size_t)lane * 8;
  const short* b0 = seg0 + (size_t)prow * LD0 + koff;   // loop-invariant bases
  const short* b1 = seg1 + (size_t)prow * LD1 + koff;

  // 2-deep rotating weight prefetch; all indices compile-time under unroll
  short8 wreg[3][NFW];
#pragma unroll
  for (int i = 0; i < NFW; ++i) wreg[0][i] = *(const short8*)(wl + i * 512);
  if (STEPS > 1) {
#pragma unroll
    for (int i = 0; i < NFW; ++i)
      wreg[1][i] = *(const short8*)(wl + (size_t)(NFTOT * 512) + i * 512);
  }

#pragma unroll
  for (int s = 0; s < STEPS; ++s) {
    if (s + 2 < STEPS) {
      const unsigned short* wn = wl + (size_t)(s + 2) * (NFTOT * 512);
#pragma unroll
      for (int i = 0; i < NFW; ++i)
        wreg[(s + 2) % 3][i] = *(const short8*)(wn + i * 512);
    }
    short8 b[4];
#pragma unroll
    for (int mf = 0; mf < 4; ++mf) {
      // act[point = mf*16+prow][kl+koff .. +7]; offset is a compile-time imm
      if (s < STEPS0) b[mf] = *(const short8*)(b0 + mf * 16 * LD0 + s * 32);
      else            b[mf] = *(const short8*)(b1 + mf * 16 * LD1 + (s - STEPS0) * 32);
    }
#pragma unroll
    for (int mf = 0; mf < 4; ++mf)
#pragma unroll
      for (int i = 0; i < NFW; ++i)
        acc[mf][i] = __builtin_amdgcn_mfma_f32_16x16x32_bf16(wreg[s % 3][i], b[mf], acc[mf][i], 0, 0, 0);
  }
  __syncthreads();   // all waves' K-loop reads complete before in-place writes
  // D^T C/D layout: channel n = (wave*NFW+i)*16 + r4 + r, point = mf*16 + prow
  short* dstb = dst + (size_t)prow * AS + wave * NFW * 16 + r4;  // loop-invariant base
#pragma unroll
  for (int i = 0; i < NFW; ++i) {
#pragma unroll
    for (int mf = 0; mf < 4; ++mf) {
      float v0 = fmaxf(acc[mf][i][0], 0.f);
      float v1 = fmaxf(acc[mf][i][1], 0.f);
      float v2 = fmaxf(acc[mf][i][2], 0.f);
      float v3 = fmaxf(acc[mf][i][3], 0.f);
      __hip_bfloat162 h01 = __float22bfloat162_rn(make_float2(v0, v1));
      __hip_bfloat162 h23 = __float22bfloat162_rn(make_float2(v2, v3));
      int2 pk;
      pk.x = *(const int*)&h01;
      pk.y = *(const int*)&h23;
      *(int2*)(dstb + mf * 16 * AS + i * 16) = pk;   // compile-time imm offset
    }
  }
  __syncthreads();
}

__global__ __launch_bounds__(NTHR, 3)   // 3 blocks/CU: see register-budget note
void nerf_fused(NerfArgs A) {
  __shared__ alignas(16) short act[TM * AS];   // 34816 B
  __shared__ alignas(16) short pbuf[TM * PS];  // 10240 B  -> 45056 B total
  const int tid = threadIdx.x;
  const int lane = tid & 63, wave = tid >> 6;
  const size_t gbase = (size_t)blockIdx.x * TM;

  // pts embed, parallel over (row, dim): 192 threads; col 63 zero by the rest
  if (tid < 192) {
    int row = tid & 63, dim = tid >> 6;
    float x = A.pts[(gbase + row) * 3 + dim];
    short* pr = pbuf + row * PS;
    pr[dim] = (short)f2b(x);
    float fr = 1.f;
    for (int q = 0; q < 10; ++q) {
      pr[3 + q * 6 + dim]     = (short)f2b(sinf(x * fr));
      pr[3 + q * 6 + 3 + dim] = (short)f2b(cosf(x * fr));
      fr *= 2.f;
    }
  } else {
    pbuf[(tid - 192) * PS + 63] = 0;
  }
  __syncthreads();

  const short* actp = act;
  short*       actw = act;
  const short* pbp  = pbuf;
  const unsigned short* ws = A.ws;

  gemm_g<16, 4,  2, 2, PS, AS>(ws + 0,      pbp,  actp, A.bias[0], actw, tid);
  gemm_g<16, 4,  8, 8, AS, AS>(ws + 16384,  actp, actp, A.bias[1], actw, tid);
  gemm_g<16, 4,  8, 8, AS, AS>(ws + 81920,  actp, actp, A.bias[2], actw, tid);
  gemm_g<16, 4,  8, 8, AS, AS>(ws + 147456, actp, actp, A.bias[3], actw, tid);
  gemm_g<16, 4,  8, 8, AS, AS>(ws + 212992, actp, actp, A.bias[4], actw, tid);
  gemm_g<16, 4, 10, 8, AS, PS>(ws + 278528, actp, pbp,  A.bias[5], actw, tid);

  // p dead: dirs embed into pbuf (cols 0..26; 27..31 zero) + d output.
  // d written as 27 CONTIGUOUS f32 per thread (measured clean WRITE=31MB).
  // Scattered per-dim stores (R6-R8) caused partial-line RMW thrash under L2
  // pressure: WRITE 269MB / FETCH +100MB. Keep contiguous.
  if (tid >= 64 && tid < 128) {
    int row = tid - 64;
    size_t g = gbase + row;
    float x0 = A.dirs[g * 3 + 0];
    float x1 = A.dirs[g * 3 + 1];
    float x2 = A.dirs[g * 3 + 2];
    float vals[27];
    vals[0] = x0; vals[1] = x1; vals[2] = x2;
    float fr = 1.f;
    for (int q = 0; q < 4; ++q) {
      vals[3 + q * 6 + 0] = sinf(x0 * fr);
      vals[3 + q * 6 + 1] = sinf(x1 * fr);
      vals[3 + q * 6 + 2] = sinf(x2 * fr);
      vals[3 + q * 6 + 3] = cosf(x0 * fr);
      vals[3 + q * 6 + 4] = cosf(x1 * fr);
      vals[3 + q * 6 + 5] = cosf(x2 * fr);
      fr *= 2.f;
    }
    short* dr = pbuf + row * PS;
    float* og = A.out + (size_t)4 * NPTS + g * 27;
    for (int j = 0; j < 27; ++j) {
      dr[j] = (short)f2b(vals[j]);
      og[j] = vals[j];
    }
    for (int j = 27; j < 32; ++j) dr[j] = 0;
  }
  // no barrier needed: L6's epilogue barriers order these writes before r0's reads

  gemm_g<16, 4,  8, 8, AS, AS>(ws + 360448, actp, actp, A.bias[6], actw, tid);
  gemm_g<16, 4,  8, 8, AS, AS>(ws + 425984, actp, actp, A.bias[7], actw, tid);

  // sigma head (SIGMA_MUL=0 -> passthrough): point = wave*16+(lane&15), k-quarter = lane>>4
  {
    int p = wave * 16 + (lane & 15);
    int q = lane >> 4;
    float s = 0.f;
    for (int c8 = 0; c8 < 8; ++c8) {
      int k0 = q * 64 + c8 * 8;
      short8 v = *(const short8*)(act + p * AS + k0);
      const float4 w0 = *(const float4*)(A.Wsig + k0);
      const float4 w1 = *(const float4*)(A.Wsig + k0 + 4);
      s += b2f((unsigned short)v[0]) * w0.x + b2f((unsigned short)v[1]) * w0.y
         + b2f((unsigned short)v[2]) * w0.z + b2f((unsigned short)v[3]) * w0.w
         + b2f((unsigned short)v[4]) * w1.x + b2f((unsigned short)v[5]) * w1.y
         + b2f((unsigned short)v[6]) * w1.z + b2f((unsigned short)v[7]) * w1.w;
    }
    s += __shfl_xor(s, 16);
    s += __shfl_xor(s, 32);
    if (q == 0) A.out[(size_t)3 * NPTS + gbase + p] = s + A.bsig[0];
  }
  // sigma reads of act are ordered before rm's in-place writes by rm's pre-epilogue barrier

  gemm_g<16, 4,  8, 8, AS, AS>(ws + 491520, actp, actp, A.bias[8], actw, tid);
  gemm_g< 8, 2,  9, 8, AS, PS>(ws + 557056, actp, pbp,  A.bias[9], actw, tid);

  // rgb head: sigmoid(fea[128] @ Wr1^T + br1): point = wave*16+(lane&15), k-quarter = lane>>4
  {
    int p = wave * 16 + (lane & 15);
    int q = lane >> 4;
    float s0 = 0.f, s1 = 0.f, s2 = 0.f;
    for (int c8 = 0; c8 < 4; ++c8) {
      int k0 = q * 32 + c8 * 8;
      short8 v = *(const short8*)(act + p * AS + k0);
#pragma unroll
      for (int j = 0; j < 8; ++j) {
        float fv = b2f((unsigned short)v[j]);
        s0 += fv * A.Wr1[k0 + j];
        s1 += fv * A.Wr1[128 + k0 + j];
        s2 += fv * A.Wr1[256 + k0 + j];
      }
    }
    s0 += __shfl_xor(s0, 16); s0 += __shfl_xor(s0, 32);
    s1 += __shfl_xor(s1, 16); s1 += __shfl_xor(s1, 32);
    s2 += __shfl_xor(s2, 16); s2 += __shfl_xor(s2, 32);
    if (q == 0) {
      size_t g = gbase + p;
      A.out[g * 3 + 0] = 1.f / (1.f + expf(-(s0 + A.br1[0])));
      A.out[g * 3 + 1] = 1.f / (1.f + expf(-(s1 + A.br1[1])));
      A.out[g * 3 + 2] = 1.f / (1.f + expf(-(s2 + A.br1[2])));
    }
  }
}

extern "C" void kernel_launch(void* const* d_in, const int* in_sizes, int n_in,
                              void* d_out, int out_size, void* d_ws, size_t ws_size,
                              hipStream_t stream) {
  // input order: pts, dirs, (Wb_i, bb_i)*8, Wsig, bsig, Wrm, brm, Wr0, br0, Wr1, br1
  PrepArgs pp;
  const int       widx[10]  = {2, 4, 6, 8, 10, 12, 14, 16, 20, 22};
  const long long doffs[10] = {0, 16384, 81920, 147456, 212992, 278528,
                               360448, 425984, 491520, 557056};
  const int stv[10] = {2, 8, 8, 8, 8, 10, 8, 8, 8, 9};
  const int ksv[10] = {63, 256, 256, 256, 256, 319, 256, 256, 256, 283};
  const int mdv[10] = {1, 0, 0, 0, 0, 2, 0, 0, 0, 1};
  const int nfv[10] = {16, 16, 16, 16, 16, 16, 16, 16, 16, 8};
  pp.ws = (unsigned short*)d_ws;   // needs WS_SHORTS*2 = 1.19 MB (verified fits)
  for (int j = 0; j < 10; ++j) {
    pp.src[j] = (const float*)d_in[widx[j]];
    pp.dst[j] = doffs[j]; pp.steps[j] = stv[j]; pp.ksrc[j] = ksv[j];
    pp.mode[j] = mdv[j]; pp.nf16[j] = nfv[j];
  }
  prep_weights<<<dim3(10, 10), dim3(256), 0, stream>>>(pp);

  NerfArgs na;
  na.pts  = (const float*)d_in[0];
  na.dirs = (const float*)d_in[1];
  na.ws   = (const unsigned short*)d_ws;
  for (int i = 0; i < 8; ++i) na.bias[i] = (const float*)d_in[3 + 2 * i];
  na.bias[8] = (const float*)d_in[21];  // brm
  na.bias[9] = (const float*)d_in[23];  // br0
  na.Wsig = (const float*)d_in[18];
  na.bsig = (const float*)d_in[19];
  na.Wr1  = (const float*)d_in[24];
  na.br1  = (const float*)d_in[25];
  na.out  = (float*)d_out;
  nerf_fused<<<dim3(NPTS / TM), dim3(NTHR), 0, stream>>>(na);
}